// Round 6
// baseline (135.858 us; speedup 1.0000x reference)
//
#include <hip/hip_runtime.h>

#define D 300
#define KP 328            // padded K stride (elements); 656 B rows
#define KSTEPS 10         // 320 / 32
#define ROWS 128          // X rows per block
#define WPB 64            // words per block
#define CH_B 20992        // 32 cols * KP * 2 bytes
#define BUF_STRIDE 21504  // padded to 21*1024
#define NSEG 21

typedef __attribute__((ext_vector_type(4))) float f32x4;
typedef __attribute__((ext_vector_type(8))) short bf16x8;

__device__ inline unsigned short f2bf(float f) {
  unsigned int u = __float_as_uint(f);
  unsigned int r = (u + 0x7fffu + ((u >> 16) & 1u)) >> 16;
  return (unsigned short)r;
}

__device__ inline void gload_lds16(const void* g, void* l) {
  __builtin_amdgcn_global_load_lds(
      (const __attribute__((address_space(1))) unsigned int*)g,
      (__attribute__((address_space(3))) unsigned int*)l, 16, 0, 0);
}

// wt[n][k] = W[k][n&511] bf16; rows 0-511=Wq, 512-1023=Wk, 1024-1535=Wv; k>=300 zero
__global__ __launch_bounds__(512) void prep_weights(
    const float* __restrict__ Wq, const float* __restrict__ Wk,
    const float* __restrict__ Wv, unsigned short* __restrict__ wt) {
  int idx = blockIdx.x * 512 + threadIdx.x;
  if (idx >= 1536 * KP) return;
  int n = idx / KP, k = idx - n * KP;
  const float* src = (n < 512) ? Wq : ((n < 1024) ? Wk : Wv);
  int col = n & 511;
  float v = (k < D) ? src[k * 512 + col] : 0.0f;
  wt[idx] = f2bf(v);
}

__global__ __launch_bounds__(512, 4) void fused_attn(
    const float* __restrict__ charv, const float* __restrict__ wordv,
    const unsigned short* __restrict__ wt,
    const float* __restrict__ bk, const float* __restrict__ bq,
    const float* __restrict__ bv, float* __restrict__ out) {
  extern __shared__ char lds[];
  float* biasL = (float*)(lds + 2 * BUF_STRIDE);  // [1536]
  float* sS    = biasL + 1536;                    // [2 cg][64 w][4]
  float* sAt   = sS + 512;                        // [64 w][4]

  const int tid  = threadIdx.x;
  const int wid  = tid >> 6;
  const int lane = tid & 63;
  const int lrow = lane & 15;
  const int kgrp = lane >> 4;
  const int rg   = wid >> 1;   // 0..3 : rows rg*32 .. +32
  const int cg   = wid & 1;    // 0..1 : 16-col half of each 32-col chunk

  // chunk t: 0..31 alternate Q_g (even) / K_g (odd), g = t>>1, 32 cols each;
  //          32..47 = V_g, g = t-32.  buffer = t & 1.
  auto stage = [&](int t) {
    long base = (t < 32) ? ((long)((t & 1) * 512 + (t >> 1) * 32) * KP * 2)
                         : ((long)(1024 + (t - 32) * 32) * KP * 2);
    const char* srcb = (const char*)wt + base;
    char* dst = lds + (t & 1) * BUF_STRIDE;
    for (int j = wid; j < NSEG; j += 8) {
      int off = j * 1024 + lane * 16;
      const char* src = (off < CH_B) ? (srcb + off) : ((const char*)wt + lane * 16);
      gload_lds16(src, dst + j * 1024);
    }
  };

  // ---- prologue: stage chunk 0 (Q0 -> buf0), biases -> LDS, X frags -> regs
  stage(0);
  for (int i = tid; i < 1536; i += 512) {
    float v = (i < 512) ? bq[i] : ((i < 1024) ? bk[i - 512] : bv[i - 1024]);
    biasL[i] = v;
  }

  bf16x8 a[2][KSTEPS];
#pragma unroll
  for (int rt = 0; rt < 2; ++rt) {
    int row = blockIdx.x * ROWS + rg * 32 + rt * 16 + lrow;
    const float* rp = ((row & 1) ? charv : wordv) + (row >> 1) * D;
#pragma unroll
    for (int ks = 0; ks < KSTEPS; ++ks) {
      int k0 = ks * 32 + kgrp * 8;
      float4 lo = {0.f, 0.f, 0.f, 0.f}, hi = {0.f, 0.f, 0.f, 0.f};
      if (k0 + 8 <= D) {
        lo = *(const float4*)(rp + k0);
        hi = *(const float4*)(rp + k0 + 4);
      } else if (k0 < D) {
        lo = *(const float4*)(rp + k0);
      }
      bf16x8 v;
      v[0] = (short)f2bf(lo.x); v[1] = (short)f2bf(lo.y);
      v[2] = (short)f2bf(lo.z); v[3] = (short)f2bf(lo.w);
      v[4] = (short)f2bf(hi.x); v[5] = (short)f2bf(hi.y);
      v[6] = (short)f2bf(hi.z); v[7] = (short)f2bf(hi.w);
      a[rt][ks] = v;
    }
  }
  __syncthreads();  // chunk 0 landed, biases visible

  float p[2][8];
#pragma unroll
  for (int rt = 0; rt < 2; ++rt)
#pragma unroll
    for (int t = 0; t < 8; ++t) p[rt][t] = 0.f;

  // ---- Phase A: 16 (Q_g, K_g) chunk pairs, 2-phase pipeline
  for (int g = 0; g < 16; ++g) {
    f32x4 accQ[2];
    stage(2 * g + 1);  // K_g -> buf1, lands during Q compute
    {
      float bqv = biasL[g * 32 + cg * 16 + lrow];
#pragma unroll
      for (int rt = 0; rt < 2; ++rt) accQ[rt] = (f32x4){bqv, bqv, bqv, bqv};
      const unsigned short* bp =
          (const unsigned short*)lds + (cg * 16 + lrow) * KP + kgrp * 8;
#pragma unroll
      for (int ks = 0; ks < KSTEPS; ++ks) {
        bf16x8 b = *(const bf16x8*)(bp + ks * 32);
        accQ[0] = __builtin_amdgcn_mfma_f32_16x16x32_bf16(a[0][ks], b, accQ[0], 0, 0, 0);
        accQ[1] = __builtin_amdgcn_mfma_f32_16x16x32_bf16(a[1][ks], b, accQ[1], 0, 0, 0);
      }
    }
    __syncthreads();

    stage(2 * g + 2);  // next Q (or V_0 at g=15) -> buf0, lands during K compute
    {
      float bkv = biasL[512 + g * 32 + cg * 16 + lrow];
      f32x4 accK[2];
#pragma unroll
      for (int rt = 0; rt < 2; ++rt) accK[rt] = (f32x4){bkv, bkv, bkv, bkv};
      const unsigned short* bp =
          (const unsigned short*)(lds + BUF_STRIDE) + (cg * 16 + lrow) * KP + kgrp * 8;
#pragma unroll
      for (int ks = 0; ks < KSTEPS; ++ks) {
        bf16x8 b = *(const bf16x8*)(bp + ks * 32);
        accK[0] = __builtin_amdgcn_mfma_f32_16x16x32_bf16(a[0][ks], b, accK[0], 0, 0, 0);
        accK[1] = __builtin_amdgcn_mfma_f32_16x16x32_bf16(a[1][ks], b, accK[1], 0, 0, 0);
      }
      // lane-local score partials (same lane holds Q and K for same (word,col))
#pragma unroll
      for (int rt = 0; rt < 2; ++rt)
#pragma unroll
        for (int wl = 0; wl < 2; ++wl)
#pragma unroll
          for (int i = 0; i < 2; ++i)
#pragma unroll
            for (int j = 0; j < 2; ++j)
              p[rt][wl * 4 + i * 2 + j] += accQ[rt][wl * 2 + i] * accK[rt][wl * 2 + j];
    }
    __syncthreads();
  }

  // ---- scores: reduce over 16 col-lanes, combine cg halves, softmax
#pragma unroll
  for (int rt = 0; rt < 2; ++rt)
#pragma unroll
    for (int t = 0; t < 8; ++t) {
      float v = p[rt][t];
      v += __shfl_xor(v, 1);
      v += __shfl_xor(v, 2);
      v += __shfl_xor(v, 4);
      v += __shfl_xor(v, 8);
      p[rt][t] = v;
    }
  if (lrow == 0) {
#pragma unroll
    for (int rt = 0; rt < 2; ++rt)
#pragma unroll
      for (int t = 0; t < 8; ++t) {
        int w = rg * 16 + rt * 8 + kgrp * 2 + (t >> 2);
        sS[cg * 256 + w * 4 + (t & 3)] = p[rt][t];
      }
  }
  __syncthreads();
  if (tid < 64) {
    const float sc = 0.044194173824159216f;  // 1/sqrt(512)
    float s[4];
#pragma unroll
    for (int t = 0; t < 4; ++t) s[t] = (sS[tid * 4 + t] + sS[256 + tid * 4 + t]) * sc;
#pragma unroll
    for (int i = 0; i < 2; ++i) {
      float m  = fmaxf(s[i * 2], s[i * 2 + 1]);
      float e0 = expf(s[i * 2] - m), e1 = expf(s[i * 2 + 1] - m);
      float inv = 1.0f / (e0 + e1);
      sAt[tid * 4 + i * 2]     = e0 * inv;
      sAt[tid * 4 + i * 2 + 1] = e1 * inv;
    }
  }
  __syncthreads();

  float at0[2][4], at1[2][4];
#pragma unroll
  for (int rt = 0; rt < 2; ++rt) {
    int wA = rg * 16 + rt * 8 + kgrp * 2;
#pragma unroll
    for (int t = 0; t < 4; ++t) {
      at0[rt][t] = sAt[wA * 4 + t];
      at1[rt][t] = sAt[(wA + 1) * 4 + t];
    }
  }

  // ---- Phase B: 16 V chunks + attention combine
  for (int t = 32; t < 48; ++t) {
    if (t < 47) stage(t + 1);
    const unsigned short* bufp = (const unsigned short*)(lds + (t & 1) * BUF_STRIDE);
    const int g = t - 32;
    f32x4 accV[2];
    {
      float b = biasL[1024 + g * 32 + cg * 16 + lrow];
      accV[0] = (f32x4){b, b, b, b};
      accV[1] = (f32x4){b, b, b, b};
    }
    const unsigned short* bp = bufp + (cg * 16 + lrow) * KP + kgrp * 8;
#pragma unroll
    for (int ks = 0; ks < KSTEPS; ++ks) {
      bf16x8 b = *(const bf16x8*)(bp + ks * 32);
      accV[0] = __builtin_amdgcn_mfma_f32_16x16x32_bf16(a[0][ks], b, accV[0], 0, 0, 0);
      accV[1] = __builtin_amdgcn_mfma_f32_16x16x32_bf16(a[1][ks], b, accV[1], 0, 0, 0);
    }
#pragma unroll
    for (int rt = 0; rt < 2; ++rt) {
      int gA = blockIdx.x * WPB + rg * 16 + rt * 8 + kgrp * 2;
      int h = g * 32 + cg * 16 + lrow;
      float* o = out + gA * 1024 + h;
      o[0]    = at0[rt][0] * accV[rt][0] + at0[rt][1] * accV[rt][1];
      o[512]  = at0[rt][2] * accV[rt][0] + at0[rt][3] * accV[rt][1];
      o[1024] = at1[rt][0] * accV[rt][2] + at1[rt][1] * accV[rt][3];
      o[1536] = at1[rt][2] * accV[rt][2] + at1[rt][3] * accV[rt][3];
    }
    if (t < 47) __syncthreads();
  }
}

extern "C" void kernel_launch(void* const* d_in, const int* in_sizes, int n_in,
                              void* d_out, int out_size, void* d_ws, size_t ws_size,
                              hipStream_t stream) {
  const float* charv = (const float*)d_in[0];
  const float* wordv = (const float*)d_in[1];
  const float* Wk = (const float*)d_in[2];
  const float* bk = (const float*)d_in[3];
  const float* Wq = (const float*)d_in[4];
  const float* bq = (const float*)d_in[5];
  const float* Wv = (const float*)d_in[6];
  const float* bv = (const float*)d_in[7];
  float* out = (float*)d_out;
  unsigned short* wt = (unsigned short*)d_ws;  // 1536*328*2 B

  prep_weights<<<(1536 * KP + 511) / 512, 512, 0, stream>>>(Wq, Wk, Wv, wt);

  const int lds_bytes = 2 * BUF_STRIDE + 1536 * 4 + 512 * 4 + 256 * 4;  // 52,224 B
  fused_attn<<<65536 / ROWS, 512, lds_bytes, stream>>>(charv, wordv, wt, bk, bq, bv, out);
}

// Round 7
// 102.344 us; speedup vs baseline: 1.3275x; 1.3275x over previous
//
#include <hip/hip_runtime.h>

#define D 300
#define KP 328            // padded K stride (elements); 656 B rows
#define KSTEPS 10         // 320 / 32
#define ROWS 128          // X rows per block
#define WPB 64            // words per block
#define CH_B 20992        // 32 cols * KP * 2 bytes
#define BUF_STRIDE 21504  // padded to 21*1024
#define NSEG 21

typedef __attribute__((ext_vector_type(4))) float f32x4;
typedef __attribute__((ext_vector_type(8))) short bf16x8;

__device__ inline unsigned short f2bf(float f) {
  unsigned int u = __float_as_uint(f);
  unsigned int r = (u + 0x7fffu + ((u >> 16) & 1u)) >> 16;
  return (unsigned short)r;
}

__device__ inline void gload_lds16(const void* g, void* l) {
  __builtin_amdgcn_global_load_lds(
      (const __attribute__((address_space(1))) unsigned int*)g,
      (__attribute__((address_space(3))) unsigned int*)l, 16, 0, 0);
}

// wt[n][k] = W[k][n&511] bf16; rows 0-511=Wq, 512-1023=Wk, 1024-1535=Wv; k>=300 zero
__global__ __launch_bounds__(512) void prep_weights(
    const float* __restrict__ Wq, const float* __restrict__ Wk,
    const float* __restrict__ Wv, unsigned short* __restrict__ wt) {
  int idx = blockIdx.x * 512 + threadIdx.x;
  if (idx >= 1536 * KP) return;
  int n = idx / KP, k = idx - n * KP;
  const float* src = (n < 512) ? Wq : ((n < 1024) ? Wk : Wv);
  int col = n & 511;
  float v = (k < D) ? src[k * 512 + col] : 0.0f;
  wt[idx] = f2bf(v);
}

// NOTE: no 2nd __launch_bounds__ arg — R4/R5/R6 showed it caps VGPRs at half
// the expected pool (128/128/64) and forces spill (WRITE_SIZE +80..98 MB).
__global__ __launch_bounds__(512) void fused_attn(
    const float* __restrict__ charv, const float* __restrict__ wordv,
    const unsigned short* __restrict__ wt,
    const float* __restrict__ bk, const float* __restrict__ bq,
    const float* __restrict__ bv, float* __restrict__ out) {
  extern __shared__ char lds[];
  float* biasL = (float*)(lds + 2 * BUF_STRIDE);  // [1536]
  float* sS    = biasL + 1536;                    // [2 cg][64 w][4]
  float* sAt   = sS + 512;                        // [64 w][4]

  const int tid  = threadIdx.x;
  const int wid  = tid >> 6;
  const int lane = tid & 63;
  const int lrow = lane & 15;
  const int kgrp = lane >> 4;
  const int rg   = wid >> 1;   // 0..3 : rows rg*32 .. +32
  const int cg   = wid & 1;    // 0..1 : 16-col half of each 32-col chunk

  // chunk t: 0..31 alternate Q_g (even) / K_g (odd), g = t>>1, 32 cols each;
  //          32..47 = V_g, g = t-32.  buffer = t & 1.
  auto stage = [&](int t) {
    long base = (t < 32) ? ((long)((t & 1) * 512 + (t >> 1) * 32) * KP * 2)
                         : ((long)(1024 + (t - 32) * 32) * KP * 2);
    const char* srcb = (const char*)wt + base;
    char* dst = lds + (t & 1) * BUF_STRIDE;
    for (int j = wid; j < NSEG; j += 8) {
      int off = j * 1024 + lane * 16;
      const char* src = (off < CH_B) ? (srcb + off) : ((const char*)wt + lane * 16);
      gload_lds16(src, dst + j * 1024);
    }
  };

  // ---- prologue: stage chunk 0 (Q0 -> buf0), biases -> LDS, X frags -> regs
  stage(0);
  for (int i = tid; i < 1536; i += 512) {
    float v = (i < 512) ? bq[i] : ((i < 1024) ? bk[i - 512] : bv[i - 1024]);
    biasL[i] = v;
  }

  bf16x8 a[2][KSTEPS];
#pragma unroll
  for (int rt = 0; rt < 2; ++rt) {
    int row = blockIdx.x * ROWS + rg * 32 + rt * 16 + lrow;
    const float* rp = ((row & 1) ? charv : wordv) + (row >> 1) * D;
#pragma unroll
    for (int ks = 0; ks < KSTEPS; ++ks) {
      int k0 = ks * 32 + kgrp * 8;
      float4 lo = {0.f, 0.f, 0.f, 0.f}, hi = {0.f, 0.f, 0.f, 0.f};
      if (k0 + 8 <= D) {
        lo = *(const float4*)(rp + k0);
        hi = *(const float4*)(rp + k0 + 4);
      } else if (k0 < D) {
        lo = *(const float4*)(rp + k0);
      }
      bf16x8 v;
      v[0] = (short)f2bf(lo.x); v[1] = (short)f2bf(lo.y);
      v[2] = (short)f2bf(lo.z); v[3] = (short)f2bf(lo.w);
      v[4] = (short)f2bf(hi.x); v[5] = (short)f2bf(hi.y);
      v[6] = (short)f2bf(hi.z); v[7] = (short)f2bf(hi.w);
      a[rt][ks] = v;
    }
  }
  __syncthreads();  // chunk 0 landed, biases visible

  float p[2][8];
#pragma unroll
  for (int rt = 0; rt < 2; ++rt)
#pragma unroll
    for (int t = 0; t < 8; ++t) p[rt][t] = 0.f;

  // ---- Phase A: 16 (Q_g, K_g) chunk pairs, 2-phase pipeline
  for (int g = 0; g < 16; ++g) {
    f32x4 accQ[2];
    stage(2 * g + 1);  // K_g -> buf1, lands during Q compute
    {
      float bqv = biasL[g * 32 + cg * 16 + lrow];
#pragma unroll
      for (int rt = 0; rt < 2; ++rt) accQ[rt] = (f32x4){bqv, bqv, bqv, bqv};
      const unsigned short* bp =
          (const unsigned short*)lds + (cg * 16 + lrow) * KP + kgrp * 8;
#pragma unroll
      for (int ks = 0; ks < KSTEPS; ++ks) {
        bf16x8 b = *(const bf16x8*)(bp + ks * 32);
        accQ[0] = __builtin_amdgcn_mfma_f32_16x16x32_bf16(a[0][ks], b, accQ[0], 0, 0, 0);
        accQ[1] = __builtin_amdgcn_mfma_f32_16x16x32_bf16(a[1][ks], b, accQ[1], 0, 0, 0);
      }
    }
    __syncthreads();

    stage(2 * g + 2);  // next Q (or V_0 at g=15) -> buf0, lands during K compute
    {
      float bkv = biasL[512 + g * 32 + cg * 16 + lrow];
      f32x4 accK[2];
#pragma unroll
      for (int rt = 0; rt < 2; ++rt) accK[rt] = (f32x4){bkv, bkv, bkv, bkv};
      const unsigned short* bp =
          (const unsigned short*)(lds + BUF_STRIDE) + (cg * 16 + lrow) * KP + kgrp * 8;
#pragma unroll
      for (int ks = 0; ks < KSTEPS; ++ks) {
        bf16x8 b = *(const bf16x8*)(bp + ks * 32);
        accK[0] = __builtin_amdgcn_mfma_f32_16x16x32_bf16(a[0][ks], b, accK[0], 0, 0, 0);
        accK[1] = __builtin_amdgcn_mfma_f32_16x16x32_bf16(a[1][ks], b, accK[1], 0, 0, 0);
      }
      // lane-local score partials (same lane holds Q and K for same (word,col))
#pragma unroll
      for (int rt = 0; rt < 2; ++rt)
#pragma unroll
        for (int wl = 0; wl < 2; ++wl)
#pragma unroll
          for (int i = 0; i < 2; ++i)
#pragma unroll
            for (int j = 0; j < 2; ++j)
              p[rt][wl * 4 + i * 2 + j] += accQ[rt][wl * 2 + i] * accK[rt][wl * 2 + j];
    }
    __syncthreads();
  }

  // ---- scores: reduce over 16 col-lanes, combine cg halves, softmax
#pragma unroll
  for (int rt = 0; rt < 2; ++rt)
#pragma unroll
    for (int t = 0; t < 8; ++t) {
      float v = p[rt][t];
      v += __shfl_xor(v, 1);
      v += __shfl_xor(v, 2);
      v += __shfl_xor(v, 4);
      v += __shfl_xor(v, 8);
      p[rt][t] = v;
    }
  if (lrow == 0) {
#pragma unroll
    for (int rt = 0; rt < 2; ++rt)
#pragma unroll
      for (int t = 0; t < 8; ++t) {
        int w = rg * 16 + rt * 8 + kgrp * 2 + (t >> 2);
        sS[cg * 256 + w * 4 + (t & 3)] = p[rt][t];
      }
  }
  __syncthreads();
  if (tid < 64) {
    const float sc = 0.044194173824159216f;  // 1/sqrt(512)
    float s[4];
#pragma unroll
    for (int t = 0; t < 4; ++t) s[t] = (sS[tid * 4 + t] + sS[256 + tid * 4 + t]) * sc;
#pragma unroll
    for (int i = 0; i < 2; ++i) {
      float m  = fmaxf(s[i * 2], s[i * 2 + 1]);
      float e0 = expf(s[i * 2] - m), e1 = expf(s[i * 2 + 1] - m);
      float inv = 1.0f / (e0 + e1);
      sAt[tid * 4 + i * 2]     = e0 * inv;
      sAt[tid * 4 + i * 2 + 1] = e1 * inv;
    }
  }
  __syncthreads();

  float at0[2][4], at1[2][4];
#pragma unroll
  for (int rt = 0; rt < 2; ++rt) {
    int wA = rg * 16 + rt * 8 + kgrp * 2;
#pragma unroll
    for (int t = 0; t < 4; ++t) {
      at0[rt][t] = sAt[wA * 4 + t];
      at1[rt][t] = sAt[(wA + 1) * 4 + t];
    }
  }

  // ---- Phase B: 16 V chunks + attention combine
  for (int t = 32; t < 48; ++t) {
    if (t < 47) stage(t + 1);
    const unsigned short* bufp = (const unsigned short*)(lds + (t & 1) * BUF_STRIDE);
    const int g = t - 32;
    f32x4 accV[2];
    {
      float b = biasL[1024 + g * 32 + cg * 16 + lrow];
      accV[0] = (f32x4){b, b, b, b};
      accV[1] = (f32x4){b, b, b, b};
    }
    const unsigned short* bp = bufp + (cg * 16 + lrow) * KP + kgrp * 8;
#pragma unroll
    for (int ks = 0; ks < KSTEPS; ++ks) {
      bf16x8 b = *(const bf16x8*)(bp + ks * 32);
      accV[0] = __builtin_amdgcn_mfma_f32_16x16x32_bf16(a[0][ks], b, accV[0], 0, 0, 0);
      accV[1] = __builtin_amdgcn_mfma_f32_16x16x32_bf16(a[1][ks], b, accV[1], 0, 0, 0);
    }
#pragma unroll
    for (int rt = 0; rt < 2; ++rt) {
      int gA = blockIdx.x * WPB + rg * 16 + rt * 8 + kgrp * 2;
      int h = g * 32 + cg * 16 + lrow;
      float* o = out + gA * 1024 + h;
      o[0]    = at0[rt][0] * accV[rt][0] + at0[rt][1] * accV[rt][1];
      o[512]  = at0[rt][2] * accV[rt][0] + at0[rt][3] * accV[rt][1];
      o[1024] = at1[rt][0] * accV[rt][2] + at1[rt][1] * accV[rt][3];
      o[1536] = at1[rt][2] * accV[rt][2] + at1[rt][3] * accV[rt][3];
    }
    if (t < 47) __syncthreads();
  }
}

extern "C" void kernel_launch(void* const* d_in, const int* in_sizes, int n_in,
                              void* d_out, int out_size, void* d_ws, size_t ws_size,
                              hipStream_t stream) {
  const float* charv = (const float*)d_in[0];
  const float* wordv = (const float*)d_in[1];
  const float* Wk = (const float*)d_in[2];
  const float* bk = (const float*)d_in[3];
  const float* Wq = (const float*)d_in[4];
  const float* bq = (const float*)d_in[5];
  const float* Wv = (const float*)d_in[6];
  const float* bv = (const float*)d_in[7];
  float* out = (float*)d_out;
  unsigned short* wt = (unsigned short*)d_ws;  // 1536*328*2 B

  prep_weights<<<(1536 * KP + 511) / 512, 512, 0, stream>>>(Wq, Wk, Wv, wt);

  const int lds_bytes = 2 * BUF_STRIDE + 1536 * 4 + 512 * 4 + 256 * 4;  // 52,224 B
  fused_attn<<<65536 / ROWS, 512, lds_bytes, stream>>>(charv, wordv, wt, bk, bq, bv, out);
}